// Round 2
// baseline (232.946 us; speedup 1.0000x reference)
//
#include <hip/hip_runtime.h>
#include <hip/hip_bf16.h>

// MSDSA: multi-scale deformable self-attention, B=1, C=256, H=W=64, N=4096, 8 heads x 32 dim.
// Inputs/outputs are FLOAT32 (harness threshold arithmetic proves no bf16 eps floor).
// Pipeline:
//  1) transpose x (C,N) -> xTf (N,C) f32 + xTb (N,C) bf16
//  2) combine dwconv weights (w3/w5/w7 * offset_weights) -> wcomb (49,256) f32
//  2b) cast wq/wk/wv/wo to bf16
//  3) per-pixel: conv+relu+offproj -> offset -> tanh grid -> bilinear sample (all f32) -> xsT bf16
//  4) GEMMs (bf16 MFMA, f32 acc): q_t=(xT)(wq^T); k_t=(xsT)(wk^T); vv=(wv)(xsT^T)
//  5) flash attention per (head, query-image-row) block, factorized Manhattan decay
//  6) d_out = (wo)(att^T) (C,N) f32

typedef __bf16 bf16x8 __attribute__((ext_vector_type(8)));
typedef __bf16 bf16x4 __attribute__((ext_vector_type(4)));
typedef float f32x4 __attribute__((ext_vector_type(4)));

__device__ __forceinline__ f32x4 mfma16(bf16x8 a, bf16x8 b, f32x4 c) {
    return __builtin_amdgcn_mfma_f32_16x16x32_bf16(a, b, c, 0, 0, 0);
}

// ---------------- 1) transpose (256,4096) f32 -> (4096,256) f32 + bf16 ----------------
__global__ void transpose_kernel(const float* __restrict__ x,
                                 float* __restrict__ xTf,
                                 __hip_bfloat16* __restrict__ xTb) {
    __shared__ float tile[32][33];
    const int p0 = blockIdx.x * 32, c0 = blockIdx.y * 32;
    const int tx = threadIdx.x, ty = threadIdx.y; // (32,8)
#pragma unroll
    for (int i = 0; i < 4; ++i)
        tile[ty + i * 8][tx] = x[(size_t)(c0 + ty + i * 8) * 4096 + p0 + tx];
    __syncthreads();
#pragma unroll
    for (int i = 0; i < 4; ++i) {
        const float v = tile[tx][ty + i * 8];
        const size_t o = (size_t)(p0 + ty + i * 8) * 256 + c0 + tx;
        xTf[o] = v;
        xTb[o] = __float2bfloat16(v);
    }
}

// ---------------- 2) combined depthwise weights ----------------
__global__ void wcomb_kernel(const float* __restrict__ w3,
                             const float* __restrict__ w5,
                             const float* __restrict__ w7,
                             const float* __restrict__ ow,
                             float* __restrict__ wcomb) {
    const int i = blockIdx.x;      // 0..48
    const int c = threadIdx.x;     // 0..255
    const int dy = i / 7, dx = i % 7;
    float val = ow[2] * w7[c * 49 + i];
    if (dy >= 1 && dy <= 5 && dx >= 1 && dx <= 5)
        val += ow[1] * w5[c * 25 + (dy - 1) * 5 + (dx - 1)];
    if (dy >= 2 && dy <= 4 && dx >= 2 && dx <= 4)
        val += ow[0] * w3[c * 9 + (dy - 2) * 3 + (dx - 2)];
    wcomb[i * 256 + c] = val;
}

// ---------------- 2b) cast 4 weight matrices (256x256 f32) -> bf16 ----------------
__global__ void cvt_w_kernel(const float* __restrict__ wq, const float* __restrict__ wk,
                             const float* __restrict__ wv, const float* __restrict__ wo,
                             __hip_bfloat16* __restrict__ out) {
    const int i = blockIdx.x * 256 + threadIdx.x;   // 0..65535
    const float* src = (blockIdx.y == 0) ? wq : (blockIdx.y == 1) ? wk
                     : (blockIdx.y == 2) ? wv : wo;
    out[(size_t)blockIdx.y * 65536 + i] = __float2bfloat16(src[i]);
}

// ---------------- 3) offsets + bilinear sample (f32 math) ----------------
__global__ __launch_bounds__(256) void sample_kernel(
    const float* __restrict__ xTf, const float* __restrict__ wcomb,
    const float* __restrict__ wop, __hip_bfloat16* __restrict__ xsT) {
    const int p = blockIdx.x;
    const int c = threadIdx.x;
    const int py = p >> 6, px = p & 63;

    float acc = 0.f;
#pragma unroll
    for (int dy = 0; dy < 7; ++dy) {
        const int yy = py + dy - 3;
        if (yy < 0 || yy > 63) continue;
#pragma unroll
        for (int dx = 0; dx < 7; ++dx) {
            const int xx = px + dx - 3;
            if (xx < 0 || xx > 63) continue;
            acc += xTf[(size_t)(yy * 64 + xx) * 256 + c] * wcomb[(dy * 7 + dx) * 256 + c];
        }
    }
    const float rf = fmaxf(acc, 0.f);
    float sy = wop[c] * rf;         // offset channel 0 = y
    float sx = wop[256 + c] * rf;   // offset channel 1 = x
#pragma unroll
    for (int off = 32; off > 0; off >>= 1) {
        sy += __shfl_down(sy, off, 64);
        sx += __shfl_down(sx, off, 64);
    }
    __shared__ float red[8];
    const int lane = threadIdx.x & 63, wid = threadIdx.x >> 6;
    if (lane == 0) { red[wid] = sy; red[wid + 4] = sx; }
    __syncthreads();
    const float offy = red[0] + red[1] + red[2] + red[3];
    const float offx = red[4] + red[5] + red[6] + red[7];

    const float refy = ((py + 0.5f) / 63.0f) * 2.0f - 1.0f;
    const float refx = ((px + 0.5f) / 63.0f) * 2.0f - 1.0f;
    const float gy = fminf(fmaxf(refy + tanhf(offy) * 2.0f, -1.0f), 1.0f);
    const float gx = fminf(fmaxf(refx + tanhf(offx) * 2.0f, -1.0f), 1.0f);
    const float iy = (gy + 1.0f) * 31.5f;
    const float ix = (gx + 1.0f) * 31.5f;
    const float y0f = floorf(iy), x0f = floorf(ix);
    const float fy = iy - y0f, fx = ix - x0f;
    int y0 = min(max((int)y0f, 0), 63), x0 = min(max((int)x0f, 0), 63);
    int y1 = min(y0 + 1, 63), x1 = min(x0 + 1, 63);
    const float v00 = xTf[(size_t)(y0 * 64 + x0) * 256 + c];
    const float v01 = xTf[(size_t)(y0 * 64 + x1) * 256 + c];
    const float v10 = xTf[(size_t)(y1 * 64 + x0) * 256 + c];
    const float v11 = xTf[(size_t)(y1 * 64 + x1) * 256 + c];
    const float out = v00 * (1.f - fx) * (1.f - fy) + v01 * fx * (1.f - fy) +
                      v10 * (1.f - fx) * fy + v11 * fx * fy;
    xsT[(size_t)p * 256 + c] = __float2bfloat16(out);
}

// ---------------- 4) GEMM: out(M,N) = A(M,256) * B(N,256)^T, bf16 in, OutT out ----------------
template <typename OutT>
__global__ __launch_bounds__(256) void gemm_abt(const __hip_bfloat16* __restrict__ A,
                                                const __hip_bfloat16* __restrict__ B,
                                                OutT* __restrict__ out, int ldc) {
    const int m0 = blockIdx.x * 64, n0 = blockIdx.y * 64;
    const int w = threadIdx.x >> 6, lane = threadIdx.x & 63;
    const int g = lane >> 4, c = lane & 15;
    f32x4 acc[4];
#pragma unroll
    for (int nt = 0; nt < 4; ++nt) acc[nt] = (f32x4){0.f, 0.f, 0.f, 0.f};
    const __hip_bfloat16* Ar = A + (size_t)(m0 + w * 16 + c) * 256 + g * 8;
#pragma unroll
    for (int kc = 0; kc < 8; ++kc) {
        const bf16x8 a = *reinterpret_cast<const bf16x8*>(Ar + kc * 32);
#pragma unroll
        for (int nt = 0; nt < 4; ++nt) {
            const bf16x8 b = *reinterpret_cast<const bf16x8*>(
                B + (size_t)(n0 + nt * 16 + c) * 256 + kc * 32 + g * 8);
            acc[nt] = mfma16(a, b, acc[nt]);
        }
    }
#pragma unroll
    for (int nt = 0; nt < 4; ++nt)
#pragma unroll
        for (int r = 0; r < 4; ++r) {
            const size_t o = (size_t)(m0 + w * 16 + 4 * g + r) * ldc + n0 + nt * 16 + c;
            if constexpr (__is_same(OutT, float)) out[o] = acc[nt][r];
            else out[o] = __float2bfloat16(acc[nt][r]);
        }
}

// ---------------- 5) flash attention with factorized decay ----------------
// grid (64 query-rows, 8 heads), 4 waves; wave w handles m-windows {w, w+4, ...}
__global__ __launch_bounds__(256, 2) void attn_kernel(
    const __hip_bfloat16* __restrict__ q_t,  // (4096,256)
    const __hip_bfloat16* __restrict__ k_t,  // (4096,256)
    const __hip_bfloat16* __restrict__ vv,   // (256,4096)
    const float* __restrict__ beta_p,
    __hip_bfloat16* __restrict__ att)        // (4096,256)
{
    __shared__ __align__(16) char smem[35840];
    const int h = blockIdx.y;
    const int nb = blockIdx.x;   // query image row (yn)
    const int n0 = nb * 64;
    const int tid = threadIdx.x;
    const int w = tid >> 6, lane = tid & 63, g = lane >> 4, c = lane & 15;

    const float bta = fabsf(beta_p[0]) + 1e-6f;
    const float L2E = 1.4426950408889634f;
    const float c2 = L2E / bta;                       // exp(-d/b) == exp2(-d*c2)
    const float scL = 0.17677669529663687f * L2E;     // head_dim^-0.5 * log2(e)

    // register-resident decay table: L2E * exp(-|xn-xm|/b); xn-xm = 16*(dlt-3)+4g+r-c
    float d64d[7][4];
#pragma unroll
    for (int dlt = 0; dlt < 7; ++dlt)
#pragma unroll
        for (int r = 0; r < 4; ++r) {
            const int dd = 16 * (dlt - 3) + 4 * g + r - c;
            d64d[dlt][r] = L2E * exp2f(-c2 * fabsf((float)dd));
        }

    // Q fragments (A operand: m = c, k = g*8 + j)
    bf16x8 aq[4];
#pragma unroll
    for (int nt = 0; nt < 4; ++nt)
        aq[nt] = *reinterpret_cast<const bf16x8*>(
            q_t + (size_t)(n0 + nt * 16 + c) * 256 + h * 32 + g * 8);

    f32x4 o_acc[4][2];
    float m_i[4][4], l_i[4][4];
#pragma unroll
    for (int nt = 0; nt < 4; ++nt) {
        o_acc[nt][0] = (f32x4){0.f, 0.f, 0.f, 0.f};
        o_acc[nt][1] = (f32x4){0.f, 0.f, 0.f, 0.f};
#pragma unroll
        for (int r = 0; r < 4; ++r) { m_i[nt][r] = -1e30f; l_i[nt][r] = 0.f; }
    }

    __bf16* pl = (__bf16*)(smem + w * 8704);   // per-wave P buffer, 64 rows x stride 68

    for (int it = 0; it < 16; ++it) {
        const int ym = it * 4 + w;
        const int m0 = ym * 64;
        const float a2 = exp2f(-c2 * fabsf((float)(nb - ym)));  // exp(-|dy|/b)

        bf16x8 bk[4];
#pragma unroll
        for (int mt = 0; mt < 4; ++mt)
            bk[mt] = *reinterpret_cast<const bf16x8*>(
                k_t + (size_t)(m0 + mt * 16 + c) * 256 + h * 32 + g * 8);

        f32x4 s[4][4];
        const f32x4 zf = (f32x4){0.f, 0.f, 0.f, 0.f};
#pragma unroll
        for (int nt = 0; nt < 4; ++nt)
#pragma unroll
            for (int mt = 0; mt < 4; ++mt) s[nt][mt] = mfma16(aq[nt], bk[mt], zf);

        // online softmax (base-2 domain), row = 16*nt + 4*g + r, col = 16*mt + c
#pragma unroll
        for (int nt = 0; nt < 4; ++nt) {
#pragma unroll
            for (int r = 0; r < 4; ++r) {
                float l0 = fmaf(s[nt][0][r], scL, a2 * d64d[nt + 3][r]);
                float l1 = fmaf(s[nt][1][r], scL, a2 * d64d[nt + 2][r]);
                float l2 = fmaf(s[nt][2][r], scL, a2 * d64d[nt + 1][r]);
                float l3 = fmaf(s[nt][3][r], scL, a2 * d64d[nt + 0][r]);
                float mx = fmaxf(fmaxf(l0, l1), fmaxf(l2, l3));
                mx = fmaxf(mx, __shfl_xor(mx, 1));
                mx = fmaxf(mx, __shfl_xor(mx, 2));
                mx = fmaxf(mx, __shfl_xor(mx, 4));
                mx = fmaxf(mx, __shfl_xor(mx, 8));
                const float mnew = fmaxf(m_i[nt][r], mx);
                const float co = exp2f(m_i[nt][r] - mnew);
                const float p0 = exp2f(l0 - mnew), p1 = exp2f(l1 - mnew);
                const float p2 = exp2f(l2 - mnew), p3 = exp2f(l3 - mnew);
                float rs = p0 + p1 + p2 + p3;
                rs += __shfl_xor(rs, 1);
                rs += __shfl_xor(rs, 2);
                rs += __shfl_xor(rs, 4);
                rs += __shfl_xor(rs, 8);
                l_i[nt][r] = l_i[nt][r] * co + rs;
                m_i[nt][r] = mnew;
                o_acc[nt][0][r] *= co;
                o_acc[nt][1][r] *= co;
                s[nt][0][r] = p0; s[nt][1][r] = p1; s[nt][2][r] = p2; s[nt][3][r] = p3;
            }
        }

        // P (C-layout) -> LDS (n,m) for A-operand reads
#pragma unroll
        for (int nt = 0; nt < 4; ++nt)
#pragma unroll
            for (int mt = 0; mt < 4; ++mt)
#pragma unroll
                for (int r = 0; r < 4; ++r)
                    pl[(nt * 16 + 4 * g + r) * 68 + mt * 16 + c] = (__bf16)s[nt][mt][r];

        bf16x8 bv[2][2];
#pragma unroll
        for (int dt = 0; dt < 2; ++dt)
#pragma unroll
            for (int mc = 0; mc < 2; ++mc)
                bv[dt][mc] = *reinterpret_cast<const bf16x8*>(
                    vv + (size_t)(h * 32 + dt * 16 + c) * 4096 + m0 + mc * 32 + g * 8);

#pragma unroll
        for (int nt = 0; nt < 4; ++nt) {
#pragma unroll
            for (int mc = 0; mc < 2; ++mc) {
                const __bf16* pr = pl + (nt * 16 + c) * 68 + mc * 32 + g * 8;
                const bf16x4 lo = *reinterpret_cast<const bf16x4*>(pr);
                const bf16x4 hi = *reinterpret_cast<const bf16x4*>(pr + 4);
                const bf16x8 pa = __builtin_shufflevector(lo, hi, 0, 1, 2, 3, 4, 5, 6, 7);
                o_acc[nt][0] = mfma16(pa, bv[0][mc], o_acc[nt][0]);
                o_acc[nt][1] = mfma16(pa, bv[1][mc], o_acc[nt][1]);
            }
        }
    }

    // combine the 4 per-wave partials
    __syncthreads();
    float* ob = (float*)smem;                  // [w][row][33]
    float* ml = (float*)(smem + 33792);        // [w][row][2]
#pragma unroll
    for (int nt = 0; nt < 4; ++nt)
#pragma unroll
        for (int r = 0; r < 4; ++r) {
            const int row = nt * 16 + 4 * g + r;
            if (c == 0) {
                ml[(w * 64 + row) * 2] = m_i[nt][r];
                ml[(w * 64 + row) * 2 + 1] = l_i[nt][r];
            }
            ob[w * 2112 + row * 33 + c] = o_acc[nt][0][r];
            ob[w * 2112 + row * 33 + 16 + c] = o_acc[nt][1][r];
        }
    __syncthreads();

    const int dd = tid & 31;
    const int r0 = tid >> 5;
#pragma unroll
    for (int rr = 0; rr < 8; ++rr) {
        const int row = rr * 8 + r0;
        const float mw0 = ml[(0 * 64 + row) * 2], mw1 = ml[(1 * 64 + row) * 2];
        const float mw2 = ml[(2 * 64 + row) * 2], mw3 = ml[(3 * 64 + row) * 2];
        const float M = fmaxf(fmaxf(mw0, mw1), fmaxf(mw2, mw3));
        const float a0 = exp2f(mw0 - M), a1 = exp2f(mw1 - M);
        const float a2_ = exp2f(mw2 - M), a3 = exp2f(mw3 - M);
        const float Os = a0 * ob[0 * 2112 + row * 33 + dd] + a1 * ob[1 * 2112 + row * 33 + dd] +
                         a2_ * ob[2 * 2112 + row * 33 + dd] + a3 * ob[3 * 2112 + row * 33 + dd];
        const float Ls = a0 * ml[(0 * 64 + row) * 2 + 1] + a1 * ml[(1 * 64 + row) * 2 + 1] +
                         a2_ * ml[(2 * 64 + row) * 2 + 1] + a3 * ml[(3 * 64 + row) * 2 + 1];
        att[(size_t)(n0 + row) * 256 + h * 32 + dd] = __float2bfloat16(Os / Ls);
    }
}

extern "C" void kernel_launch(void* const* d_in, const int* in_sizes, int n_in,
                              void* d_out, int out_size, void* d_ws, size_t ws_size,
                              hipStream_t stream) {
    (void)in_sizes; (void)n_in; (void)out_size; (void)ws_size;
    const float* x    = (const float*)d_in[0];
    const float* ow   = (const float*)d_in[1];
    const float* w3   = (const float*)d_in[2];
    const float* w5   = (const float*)d_in[3];
    const float* w7   = (const float*)d_in[4];
    const float* wop  = (const float*)d_in[5];
    const float* wq   = (const float*)d_in[6];
    const float* wk   = (const float*)d_in[7];
    const float* wv   = (const float*)d_in[8];
    const float* wo   = (const float*)d_in[9];
    const float* beta = (const float*)d_in[10];

    char* ws = (char*)d_ws;
    const size_t MB = 1 << 20;
    float*          xTf = (float*)(ws);                               // 4 MB
    __hip_bfloat16* xTb = (__hip_bfloat16*)(ws + 4 * MB);             // 2 MB
    __hip_bfloat16* xsT = (__hip_bfloat16*)(ws + 6 * MB);             // 2 MB
    __hip_bfloat16* q_t = (__hip_bfloat16*)(ws + 8 * MB);             // 2 MB
    __hip_bfloat16* k_t = (__hip_bfloat16*)(ws + 10 * MB);            // 2 MB
    __hip_bfloat16* vv  = (__hip_bfloat16*)(ws + 12 * MB);            // 2 MB
    __hip_bfloat16* att = (__hip_bfloat16*)(ws + 14 * MB);            // 2 MB
    __hip_bfloat16* wb  = (__hip_bfloat16*)(ws + 16 * MB);            // 512 KB (wq,wk,wv,wo bf16)
    float* wcomb        = (float*)(ws + 16 * MB + 512 * 1024);        // 50 KB
    __hip_bfloat16* wqb = wb;
    __hip_bfloat16* wkb = wb + 65536;
    __hip_bfloat16* wvb = wb + 2 * 65536;
    __hip_bfloat16* wob = wb + 3 * 65536;

    transpose_kernel<<<dim3(128, 8), dim3(32, 8), 0, stream>>>(x, xTf, xTb);
    wcomb_kernel<<<49, 256, 0, stream>>>(w3, w5, w7, ow, wcomb);
    cvt_w_kernel<<<dim3(256, 4), 256, 0, stream>>>(wq, wk, wv, wo, wb);
    sample_kernel<<<4096, 256, 0, stream>>>(xTf, wcomb, wop, xsT);
    gemm_abt<__hip_bfloat16><<<dim3(64, 4), 256, 0, stream>>>(xTb, wqb, q_t, 256);
    gemm_abt<__hip_bfloat16><<<dim3(64, 4), 256, 0, stream>>>(xsT, wkb, k_t, 256);
    gemm_abt<__hip_bfloat16><<<dim3(4, 64), 256, 0, stream>>>(wvb, xsT, vv, 4096);
    attn_kernel<<<dim3(64, 8), 256, 0, stream>>>(q_t, k_t, vv, beta, att);
    gemm_abt<float><<<dim3(4, 64), 256, 0, stream>>>(wob, att, (float*)d_out, 4096);
}

// Round 3
// 195.502 us; speedup vs baseline: 1.1915x; 1.1915x over previous
//
#include <hip/hip_runtime.h>
#include <hip/hip_bf16.h>

// MSDSA: multi-scale deformable self-attention, B=1, C=256, H=W=64, N=4096, 8 heads x 32 dim.
// Inputs/outputs FLOAT32. Pipeline:
//  1) transpose x (C,N) -> xTf (N,C) f32 + xTb (N,C) bf16
//  2) prep: combined dwconv weights -> wcomb (49,256) f32; cast wq/wk/wv/wo -> bf16
//  3) per-pixel conv+relu+offproj -> tanh grid -> bilinear sample (f32) -> xsT bf16
//  4) GEMMs (bf16 MFMA): q_t=(xT)(wq^T); k_t=(xsT)(wk^T); vv=(wv)(xsT^T)
//  5) flash attention, FIXED-SHIFT softmax (exact: shift-invariant), factorized Manhattan decay
//  6) d_out = (wo)(att^T) f32

typedef __bf16 bf16x8 __attribute__((ext_vector_type(8)));
typedef float f32x4 __attribute__((ext_vector_type(4)));

__device__ __forceinline__ f32x4 mfma16(bf16x8 a, bf16x8 b, f32x4 c) {
    return __builtin_amdgcn_mfma_f32_16x16x32_bf16(a, b, c, 0, 0, 0);
}

// pack two f32 -> one dword of 2 bf16 (truncate): dst = (hi16(pb)<<16)|hi16(pa)
__device__ __forceinline__ unsigned pack_bf16(float pa, float pb) {
    return __builtin_amdgcn_perm(__float_as_uint(pb), __float_as_uint(pa), 0x07060302u);
}

// ---------------- 1) transpose (256,4096) f32 -> (4096,256) f32 + bf16 ----------------
__global__ void transpose_kernel(const float* __restrict__ x,
                                 float* __restrict__ xTf,
                                 __hip_bfloat16* __restrict__ xTb) {
    __shared__ float tile[32][33];
    const int p0 = blockIdx.x * 32, c0 = blockIdx.y * 32;
    const int tx = threadIdx.x, ty = threadIdx.y; // (32,8)
#pragma unroll
    for (int i = 0; i < 4; ++i)
        tile[ty + i * 8][tx] = x[(size_t)(c0 + ty + i * 8) * 4096 + p0 + tx];
    __syncthreads();
#pragma unroll
    for (int i = 0; i < 4; ++i) {
        const float v = tile[tx][ty + i * 8];
        const size_t o = (size_t)(p0 + ty + i * 8) * 256 + c0 + tx;
        xTf[o] = v;
        xTb[o] = __float2bfloat16(v);
    }
}

// ---------------- 2) prep: wcomb + weight casts (fused) ----------------
__global__ void prep_kernel(const float* __restrict__ w3, const float* __restrict__ w5,
                            const float* __restrict__ w7, const float* __restrict__ ow,
                            const float* __restrict__ wq, const float* __restrict__ wk,
                            const float* __restrict__ wv, const float* __restrict__ wo,
                            float* __restrict__ wcomb, __hip_bfloat16* __restrict__ wb) {
    const int b = blockIdx.x;
    if (b < 49) {
        const int i = b, c = threadIdx.x;
        const int dy = i / 7, dx = i % 7;
        float val = ow[2] * w7[c * 49 + i];
        if (dy >= 1 && dy <= 5 && dx >= 1 && dx <= 5)
            val += ow[1] * w5[c * 25 + (dy - 1) * 5 + (dx - 1)];
        if (dy >= 2 && dy <= 4 && dx >= 2 && dx <= 4)
            val += ow[0] * w3[c * 9 + (dy - 2) * 3 + (dx - 2)];
        wcomb[i * 256 + c] = val;
    } else {
        const int idx = (b - 49) * 256 + threadIdx.x;   // 0..262143
        const int m = idx >> 16;
        const float* src = (m == 0) ? wq : (m == 1) ? wk : (m == 2) ? wv : wo;
        wb[idx] = __float2bfloat16(src[idx & 65535]);
    }
}

// ---------------- 3) offsets + bilinear sample (f32 math) ----------------
__global__ __launch_bounds__(256) void sample_kernel(
    const float* __restrict__ xTf, const float* __restrict__ wcomb,
    const float* __restrict__ wop, __hip_bfloat16* __restrict__ xsT) {
    const int p = blockIdx.x;
    const int c = threadIdx.x;
    const int py = p >> 6, px = p & 63;

    float acc = 0.f;
#pragma unroll
    for (int dy = 0; dy < 7; ++dy) {
        const int yy = py + dy - 3;
        if (yy < 0 || yy > 63) continue;
#pragma unroll
        for (int dx = 0; dx < 7; ++dx) {
            const int xx = px + dx - 3;
            if (xx < 0 || xx > 63) continue;
            acc += xTf[(size_t)(yy * 64 + xx) * 256 + c] * wcomb[(dy * 7 + dx) * 256 + c];
        }
    }
    const float rf = fmaxf(acc, 0.f);
    float sy = wop[c] * rf;
    float sx = wop[256 + c] * rf;
#pragma unroll
    for (int off = 32; off > 0; off >>= 1) {
        sy += __shfl_down(sy, off, 64);
        sx += __shfl_down(sx, off, 64);
    }
    __shared__ float red[8];
    const int lane = threadIdx.x & 63, wid = threadIdx.x >> 6;
    if (lane == 0) { red[wid] = sy; red[wid + 4] = sx; }
    __syncthreads();
    const float offy = red[0] + red[1] + red[2] + red[3];
    const float offx = red[4] + red[5] + red[6] + red[7];

    const float refy = ((py + 0.5f) / 63.0f) * 2.0f - 1.0f;
    const float refx = ((px + 0.5f) / 63.0f) * 2.0f - 1.0f;
    const float gy = fminf(fmaxf(refy + tanhf(offy) * 2.0f, -1.0f), 1.0f);
    const float gx = fminf(fmaxf(refx + tanhf(offx) * 2.0f, -1.0f), 1.0f);
    const float iy = (gy + 1.0f) * 31.5f;
    const float ix = (gx + 1.0f) * 31.5f;
    const float y0f = floorf(iy), x0f = floorf(ix);
    const float fy = iy - y0f, fx = ix - x0f;
    int y0 = min(max((int)y0f, 0), 63), x0 = min(max((int)x0f, 0), 63);
    int y1 = min(y0 + 1, 63), x1 = min(x0 + 1, 63);
    const float v00 = xTf[(size_t)(y0 * 64 + x0) * 256 + c];
    const float v01 = xTf[(size_t)(y0 * 64 + x1) * 256 + c];
    const float v10 = xTf[(size_t)(y1 * 64 + x0) * 256 + c];
    const float v11 = xTf[(size_t)(y1 * 64 + x1) * 256 + c];
    const float out = v00 * (1.f - fx) * (1.f - fy) + v01 * fx * (1.f - fy) +
                      v10 * (1.f - fx) * fy + v11 * fx * fy;
    xsT[(size_t)p * 256 + c] = __float2bfloat16(out);
}

// ---------------- 4) GEMM body: out(M,N) = A(M,256)*B(N,256)^T ----------------
template <typename OutT>
__device__ __forceinline__ void gemm_body(const __hip_bfloat16* A, const __hip_bfloat16* B,
                                          OutT* out, int ldc, int m0, int n0) {
    const int w = threadIdx.x >> 6, lane = threadIdx.x & 63;
    const int g = lane >> 4, c = lane & 15;
    f32x4 acc[4];
#pragma unroll
    for (int nt = 0; nt < 4; ++nt) acc[nt] = (f32x4){0.f, 0.f, 0.f, 0.f};
    const __hip_bfloat16* Ar = A + (size_t)(m0 + w * 16 + c) * 256 + g * 8;
#pragma unroll
    for (int kc = 0; kc < 8; ++kc) {
        const bf16x8 a = *reinterpret_cast<const bf16x8*>(Ar + kc * 32);
#pragma unroll
        for (int nt = 0; nt < 4; ++nt) {
            const bf16x8 b = *reinterpret_cast<const bf16x8*>(
                B + (size_t)(n0 + nt * 16 + c) * 256 + kc * 32 + g * 8);
            acc[nt] = mfma16(a, b, acc[nt]);
        }
    }
#pragma unroll
    for (int nt = 0; nt < 4; ++nt)
#pragma unroll
        for (int r = 0; r < 4; ++r) {
            const size_t o = (size_t)(m0 + w * 16 + 4 * g + r) * ldc + n0 + nt * 16 + c;
            if constexpr (__is_same(OutT, float)) out[o] = acc[nt][r];
            else out[o] = __float2bfloat16(acc[nt][r]);
        }
}

template <typename OutT>
__global__ __launch_bounds__(256) void gemm_abt(const __hip_bfloat16* __restrict__ A,
                                                const __hip_bfloat16* __restrict__ B,
                                                OutT* __restrict__ out, int ldc) {
    gemm_body<OutT>(A, B, out, ldc, blockIdx.x * 64, blockIdx.y * 64);
}

// fused Q/K projection (z = 0 -> Q, z = 1 -> K)
__global__ __launch_bounds__(256) void gemm_qk(const __hip_bfloat16* __restrict__ xq,
                                               const __hip_bfloat16* __restrict__ xs,
                                               const __hip_bfloat16* __restrict__ wqb,
                                               const __hip_bfloat16* __restrict__ wkb,
                                               __hip_bfloat16* __restrict__ q_t,
                                               __hip_bfloat16* __restrict__ k_t) {
    const bool z = blockIdx.z != 0;
    gemm_body<__hip_bfloat16>(z ? xs : xq, z ? wkb : wqb, z ? k_t : q_t, 256,
                              blockIdx.x * 64, blockIdx.y * 64);
}

// ---------------- 5) flash attention, fixed-shift softmax ----------------
// grid (128, 8): block = 32 query rows (half an image row), 4 waves split m-space.
__global__ __launch_bounds__(256, 4) void attn_kernel(
    const __hip_bfloat16* __restrict__ q_t,  // (4096,256)
    const __hip_bfloat16* __restrict__ k_t,  // (4096,256)
    const __hip_bfloat16* __restrict__ vv,   // (256,4096)
    const float* __restrict__ beta_p,
    __hip_bfloat16* __restrict__ att)        // (4096,256)
{
    __shared__ __align__(16) char smem[18944];
    const int h = blockIdx.y;
    const int nb2 = blockIdx.x;
    const int n0 = nb2 * 32;
    const int yq = nb2 >> 1;          // query image row
    const int half = nb2 & 1;
    const int tid = threadIdx.x;
    const int w = tid >> 6, lane = tid & 63, g = lane >> 4, c = lane & 15;

    const float bta = fabsf(beta_p[0]) + 1e-6f;
    const float L2E = 1.4426950408889634f;
    const float c2 = L2E / bta;                       // exp(-d/b) == exp2(-d*c2)
    const float scL = 0.17677669529663687f * L2E;     // head_dim^-0.5 * log2(e)

    // decay table, half folded in: dlt2 = nt-mt+3 in [0,4] (static indexing)
    // value = L2E * exp(-|xn-xm|/b), xn-xm = 16*(dlt2-3) + 32*half + 4g+r-c
    float d64d[5][4];
#pragma unroll
    for (int dlt = 0; dlt < 5; ++dlt)
#pragma unroll
        for (int r = 0; r < 4; ++r) {
            const int dd = 16 * (dlt - 3) + 32 * half + 4 * g + r - c;
            d64d[dlt][r] = L2E * exp2f(-c2 * fabsf((float)dd));
        }

    bf16x8 aq[2];
#pragma unroll
    for (int nt = 0; nt < 2; ++nt)
        aq[nt] = *reinterpret_cast<const bf16x8*>(
            q_t + (size_t)(n0 + nt * 16 + c) * 256 + h * 32 + g * 8);

    f32x4 o_acc[2][2];
    float l_part[2][4];
#pragma unroll
    for (int nt = 0; nt < 2; ++nt) {
        o_acc[nt][0] = (f32x4){0.f, 0.f, 0.f, 0.f};
        o_acc[nt][1] = (f32x4){0.f, 0.f, 0.f, 0.f};
#pragma unroll
        for (int r = 0; r < 4; ++r) l_part[nt][r] = 0.f;
    }

    __bf16* plw = (__bf16*)smem + w * 2304;   // P^T per wave: [m=64][n stride 36]

    for (int it = 0; it < 16; ++it) {
        const int ym = it * 4 + w;
        const int m0 = ym * 64;
        const float a2 = exp2f(-c2 * fabsf((float)(yq - ym)));  // exp(-|dy|/b)

        bf16x8 bk[4];
#pragma unroll
        for (int mt = 0; mt < 4; ++mt)
            bk[mt] = *reinterpret_cast<const bf16x8*>(
                k_t + (size_t)(m0 + mt * 16 + c) * 256 + h * 32 + g * 8);
        bf16x8 bv[2][2];
#pragma unroll
        for (int dt = 0; dt < 2; ++dt)
#pragma unroll
            for (int mc = 0; mc < 2; ++mc)
                bv[dt][mc] = *reinterpret_cast<const bf16x8*>(
                    vv + (size_t)(h * 32 + dt * 16 + c) * 4096 + m0 + mc * 32 + g * 8);

        const f32x4 zf = (f32x4){0.f, 0.f, 0.f, 0.f};
#pragma unroll
        for (int nt = 0; nt < 2; ++nt) {
            f32x4 s[4];
#pragma unroll
            for (int mt = 0; mt < 4; ++mt) s[mt] = mfma16(aq[nt], bk[mt], zf);
            // fixed-shift softmax numerator: p = exp2(s*scL + bias - 3); shift cancels in O/L
#pragma unroll
            for (int mt = 0; mt < 4; ++mt) {
                float p[4];
#pragma unroll
                for (int r = 0; r < 4; ++r) {
                    const float t = fmaf(s[mt][r], scL, -3.0f);
                    const float l = fmaf(a2, d64d[nt - mt + 3][r], t);
                    p[r] = exp2f(l);
                    l_part[nt][r] += p[r];
                }
                const unsigned d0 = pack_bf16(p[0], p[1]);
                const unsigned d1 = pack_bf16(p[2], p[3]);
                *reinterpret_cast<uint2*>(plw + (16 * mt + c) * 36 + 16 * nt + 4 * g) =
                    uint2{d0, d1};
            }
        }

        // PV: A-operand reads from per-wave P^T (wave-internal ordering via lgkmcnt)
#pragma unroll
        for (int nt = 0; nt < 2; ++nt)
#pragma unroll
            for (int mc = 0; mc < 2; ++mc) {
                const __bf16* pb = plw + (32 * mc + 8 * g) * 36 + 16 * nt + c;
                bf16x8 pa;
#pragma unroll
                for (int j = 0; j < 8; ++j) pa[j] = pb[j * 36];
                o_acc[nt][0] = mfma16(pa, bv[0][mc], o_acc[nt][0]);
                o_acc[nt][1] = mfma16(pa, bv[1][mc], o_acc[nt][1]);
            }
    }

    // one-time denominator reduction across the 16 c-lanes
#pragma unroll
    for (int nt = 0; nt < 2; ++nt)
#pragma unroll
        for (int r = 0; r < 4; ++r) {
            float v = l_part[nt][r];
            v += __shfl_xor(v, 1);
            v += __shfl_xor(v, 2);
            v += __shfl_xor(v, 4);
            v += __shfl_xor(v, 8);
            l_part[nt][r] = v;
        }

    __syncthreads();
    float* ob = (float*)smem;                  // [w][32][33]
    float* lred = (float*)(smem + 18432);      // [w][32]
#pragma unroll
    for (int nt = 0; nt < 2; ++nt)
#pragma unroll
        for (int r = 0; r < 4; ++r) {
            const int row = 16 * nt + 4 * g + r;
            if (c == 0) lred[w * 32 + row] = l_part[nt][r];
            ob[w * 1056 + row * 33 + c] = o_acc[nt][0][r];
            ob[w * 1056 + row * 33 + 16 + c] = o_acc[nt][1][r];
        }
    __syncthreads();

#pragma unroll
    for (int k = 0; k < 4; ++k) {
        const int flat = k * 256 + tid;
        const int row = flat >> 5, d = flat & 31;
        const float O = ob[row * 33 + d] + ob[1056 + row * 33 + d] +
                        ob[2112 + row * 33 + d] + ob[3168 + row * 33 + d];
        const float L = lred[row] + lred[32 + row] + lred[64 + row] + lred[96 + row];
        att[(size_t)(n0 + row) * 256 + h * 32 + d] = __float2bfloat16(O / L);
    }
}

extern "C" void kernel_launch(void* const* d_in, const int* in_sizes, int n_in,
                              void* d_out, int out_size, void* d_ws, size_t ws_size,
                              hipStream_t stream) {
    (void)in_sizes; (void)n_in; (void)out_size; (void)ws_size;
    const float* x    = (const float*)d_in[0];
    const float* ow   = (const float*)d_in[1];
    const float* w3   = (const float*)d_in[2];
    const float* w5   = (const float*)d_in[3];
    const float* w7   = (const float*)d_in[4];
    const float* wop  = (const float*)d_in[5];
    const float* wq   = (const float*)d_in[6];
    const float* wk   = (const float*)d_in[7];
    const float* wv   = (const float*)d_in[8];
    const float* wo   = (const float*)d_in[9];
    const float* beta = (const float*)d_in[10];

    char* ws = (char*)d_ws;
    const size_t MB = 1 << 20;
    float*          xTf = (float*)(ws);                               // 4 MB
    __hip_bfloat16* xTb = (__hip_bfloat16*)(ws + 4 * MB);             // 2 MB
    __hip_bfloat16* xsT = (__hip_bfloat16*)(ws + 6 * MB);             // 2 MB
    __hip_bfloat16* q_t = (__hip_bfloat16*)(ws + 8 * MB);             // 2 MB
    __hip_bfloat16* k_t = (__hip_bfloat16*)(ws + 10 * MB);            // 2 MB
    __hip_bfloat16* vv  = (__hip_bfloat16*)(ws + 12 * MB);            // 2 MB
    __hip_bfloat16* att = (__hip_bfloat16*)(ws + 14 * MB);            // 2 MB
    __hip_bfloat16* wb  = (__hip_bfloat16*)(ws + 16 * MB);            // 512 KB
    float* wcomb        = (float*)(ws + 16 * MB + 512 * 1024);        // 50 KB
    __hip_bfloat16* wqb = wb;
    __hip_bfloat16* wkb = wb + 65536;
    __hip_bfloat16* wvb = wb + 2 * 65536;
    __hip_bfloat16* wob = wb + 3 * 65536;

    transpose_kernel<<<dim3(128, 8), dim3(32, 8), 0, stream>>>(x, xTf, xTb);
    prep_kernel<<<1073, 256, 0, stream>>>(w3, w5, w7, ow, wq, wk, wv, wo, wcomb, wb);
    sample_kernel<<<4096, 256, 0, stream>>>(xTf, wcomb, wop, xsT);
    gemm_qk<<<dim3(64, 4, 2), 256, 0, stream>>>(xTb, xsT, wqb, wkb, q_t, k_t);
    gemm_abt<__hip_bfloat16><<<dim3(4, 64), 256, 0, stream>>>(wvb, xsT, vv, 4096);
    attn_kernel<<<dim3(128, 8), 256, 0, stream>>>(q_t, k_t, vv, beta, att);
    gemm_abt<float><<<dim3(4, 64), 256, 0, stream>>>(wob, att, (float*)d_out, 4096);
}

// Round 4
// 194.434 us; speedup vs baseline: 1.1981x; 1.0055x over previous
//
#include <hip/hip_runtime.h>
#include <hip/hip_bf16.h>

// MSDSA: multi-scale deformable self-attention, B=1, C=256, H=W=64, N=4096, 8 heads x 32 dim.
// Inputs/outputs FLOAT32. Pipeline:
//  1) transpose x (C,N) -> xTf (N,C) f32 + xTb (N,C) bf16
//  2) prep: combined dwconv weights -> wcomb (49,256) f32; cast wq(*scaleL2E)/wk/wv/wo -> bf16
//  3) per-pixel conv+relu+offproj -> tanh grid -> bilinear sample (f32) -> xsT bf16
//  4) one dispatch: q_t=(xT)(wq^T); k_t=(xsT)(wk^T); vv=(wv)(xsT^T)  (bf16 MFMA)
//  5) flash attention: S^T tiles (n on lane&15), all-vector LDS P transpose, no-shift softmax
//  6) d_out = (wo)(att^T) f32

typedef __bf16 bf16x8 __attribute__((ext_vector_type(8)));
typedef float f32x4 __attribute__((ext_vector_type(4)));

__device__ __forceinline__ f32x4 mfma16(bf16x8 a, bf16x8 b, f32x4 c) {
    return __builtin_amdgcn_mfma_f32_16x16x32_bf16(a, b, c, 0, 0, 0);
}

// pack two f32 -> one dword of 2 bf16 (truncate)
__device__ __forceinline__ unsigned pack_bf16(float pa, float pb) {
    return __builtin_amdgcn_perm(__float_as_uint(pb), __float_as_uint(pa), 0x07060302u);
}

// ---------------- 1) transpose (256,4096) f32 -> (4096,256) f32 + bf16 ----------------
__global__ void transpose_kernel(const float* __restrict__ x,
                                 float* __restrict__ xTf,
                                 __hip_bfloat16* __restrict__ xTb) {
    __shared__ float tile[32][33];
    const int p0 = blockIdx.x * 32, c0 = blockIdx.y * 32;
    const int tx = threadIdx.x, ty = threadIdx.y; // (32,8)
#pragma unroll
    for (int i = 0; i < 4; ++i)
        tile[ty + i * 8][tx] = x[(size_t)(c0 + ty + i * 8) * 4096 + p0 + tx];
    __syncthreads();
#pragma unroll
    for (int i = 0; i < 4; ++i) {
        const float v = tile[tx][ty + i * 8];
        const size_t o = (size_t)(p0 + ty + i * 8) * 256 + c0 + tx;
        xTf[o] = v;
        xTb[o] = __float2bfloat16(v);
    }
}

// ---------------- 2) prep: wcomb + weight casts (q scaled by scale*log2e) ----------------
__global__ void prep_kernel(const float* __restrict__ w3, const float* __restrict__ w5,
                            const float* __restrict__ w7, const float* __restrict__ ow,
                            const float* __restrict__ wq, const float* __restrict__ wk,
                            const float* __restrict__ wv, const float* __restrict__ wo,
                            float* __restrict__ wcomb, __hip_bfloat16* __restrict__ wb) {
    const int b = blockIdx.x;
    if (b < 49) {
        const int i = b, c = threadIdx.x;
        const int dy = i / 7, dx = i % 7;
        float val = ow[2] * w7[c * 49 + i];
        if (dy >= 1 && dy <= 5 && dx >= 1 && dx <= 5)
            val += ow[1] * w5[c * 25 + (dy - 1) * 5 + (dx - 1)];
        if (dy >= 2 && dy <= 4 && dx >= 2 && dx <= 4)
            val += ow[0] * w3[c * 9 + (dy - 2) * 3 + (dx - 2)];
        wcomb[i * 256 + c] = val;
    } else {
        const int idx = (b - 49) * 256 + threadIdx.x;   // 0..262143
        const int m = idx >> 16;
        const float* src = (m == 0) ? wq : (m == 1) ? wk : (m == 2) ? wv : wo;
        const float sc = (m == 0) ? 0.25507535f : 1.0f;  // 32^-0.5 * log2(e)
        wb[idx] = __float2bfloat16(src[idx & 65535] * sc);
    }
}

// ---------------- 3) offsets + bilinear sample (f32 math) ----------------
__global__ __launch_bounds__(256) void sample_kernel(
    const float* __restrict__ xTf, const float* __restrict__ wcomb,
    const float* __restrict__ wop, __hip_bfloat16* __restrict__ xsT) {
    const int p = blockIdx.x;
    const int c = threadIdx.x;
    const int py = p >> 6, px = p & 63;

    float acc = 0.f;
#pragma unroll
    for (int dy = 0; dy < 7; ++dy) {
        const int yy = py + dy - 3;
        if (yy < 0 || yy > 63) continue;
#pragma unroll
        for (int dx = 0; dx < 7; ++dx) {
            const int xx = px + dx - 3;
            if (xx < 0 || xx > 63) continue;
            acc += xTf[(size_t)(yy * 64 + xx) * 256 + c] * wcomb[(dy * 7 + dx) * 256 + c];
        }
    }
    const float rf = fmaxf(acc, 0.f);
    float sy = wop[c] * rf;
    float sx = wop[256 + c] * rf;
#pragma unroll
    for (int off = 32; off > 0; off >>= 1) {
        sy += __shfl_down(sy, off, 64);
        sx += __shfl_down(sx, off, 64);
    }
    __shared__ float red[8];
    const int lane = threadIdx.x & 63, wid = threadIdx.x >> 6;
    if (lane == 0) { red[wid] = sy; red[wid + 4] = sx; }
    __syncthreads();
    const float offy = red[0] + red[1] + red[2] + red[3];
    const float offx = red[4] + red[5] + red[6] + red[7];

    const float refy = ((py + 0.5f) / 63.0f) * 2.0f - 1.0f;
    const float refx = ((px + 0.5f) / 63.0f) * 2.0f - 1.0f;
    const float gy = fminf(fmaxf(refy + tanhf(offy) * 2.0f, -1.0f), 1.0f);
    const float gx = fminf(fmaxf(refx + tanhf(offx) * 2.0f, -1.0f), 1.0f);
    const float iy = (gy + 1.0f) * 31.5f;
    const float ix = (gx + 1.0f) * 31.5f;
    const float y0f = floorf(iy), x0f = floorf(ix);
    const float fy = iy - y0f, fx = ix - x0f;
    int y0 = min(max((int)y0f, 0), 63), x0 = min(max((int)x0f, 0), 63);
    int y1 = min(y0 + 1, 63), x1 = min(x0 + 1, 63);
    const float v00 = xTf[(size_t)(y0 * 64 + x0) * 256 + c];
    const float v01 = xTf[(size_t)(y0 * 64 + x1) * 256 + c];
    const float v10 = xTf[(size_t)(y1 * 64 + x0) * 256 + c];
    const float v11 = xTf[(size_t)(y1 * 64 + x1) * 256 + c];
    const float out = v00 * (1.f - fx) * (1.f - fy) + v01 * fx * (1.f - fy) +
                      v10 * (1.f - fx) * fy + v11 * fx * fy;
    xsT[(size_t)p * 256 + c] = __float2bfloat16(out);
}

// ---------------- 4) GEMM body: out(M,N) = A(M,256)*B(N,256)^T ----------------
template <typename OutT>
__device__ __forceinline__ void gemm_body(const __hip_bfloat16* A, const __hip_bfloat16* B,
                                          OutT* out, int ldc, int m0, int n0) {
    const int w = threadIdx.x >> 6, lane = threadIdx.x & 63;
    const int g = lane >> 4, c = lane & 15;
    f32x4 acc[4];
#pragma unroll
    for (int nt = 0; nt < 4; ++nt) acc[nt] = (f32x4){0.f, 0.f, 0.f, 0.f};
    const __hip_bfloat16* Ar = A + (size_t)(m0 + w * 16 + c) * 256 + g * 8;
#pragma unroll
    for (int kc = 0; kc < 8; ++kc) {
        const bf16x8 a = *reinterpret_cast<const bf16x8*>(Ar + kc * 32);
#pragma unroll
        for (int nt = 0; nt < 4; ++nt) {
            const bf16x8 b = *reinterpret_cast<const bf16x8*>(
                B + (size_t)(n0 + nt * 16 + c) * 256 + kc * 32 + g * 8);
            acc[nt] = mfma16(a, b, acc[nt]);
        }
    }
#pragma unroll
    for (int nt = 0; nt < 4; ++nt)
#pragma unroll
        for (int r = 0; r < 4; ++r) {
            const size_t o = (size_t)(m0 + w * 16 + 4 * g + r) * ldc + n0 + nt * 16 + c;
            if constexpr (__is_same(OutT, float)) out[o] = acc[nt][r];
            else out[o] = __float2bfloat16(acc[nt][r]);
        }
}

// fused Q/K/V projections: z=0 Q, z=1 K, z=2 V
__global__ __launch_bounds__(256) void gemm_qkv(const __hip_bfloat16* __restrict__ xq,
                                                const __hip_bfloat16* __restrict__ xs,
                                                const __hip_bfloat16* __restrict__ wb,
                                                __hip_bfloat16* __restrict__ q_t,
                                                __hip_bfloat16* __restrict__ k_t,
                                                __hip_bfloat16* __restrict__ vv) {
    const int z = blockIdx.z;
    if (z == 0)
        gemm_body<__hip_bfloat16>(xq, wb, q_t, 256, blockIdx.x * 64, blockIdx.y * 64);
    else if (z == 1)
        gemm_body<__hip_bfloat16>(xs, wb + 65536, k_t, 256, blockIdx.x * 64, blockIdx.y * 64);
    else
        gemm_body<__hip_bfloat16>(wb + 2 * 65536, xs, vv, 4096, blockIdx.y * 64,
                                  blockIdx.x * 64);
}

template <typename OutT>
__global__ __launch_bounds__(256) void gemm_abt(const __hip_bfloat16* __restrict__ A,
                                                const __hip_bfloat16* __restrict__ B,
                                                OutT* __restrict__ out, int ldc) {
    gemm_body<OutT>(A, B, out, ldc, blockIdx.x * 64, blockIdx.y * 64);
}

// ---------------- 5) flash attention, S^T form, all-vector LDS transpose ----------------
// grid (128, 8): block = 32 query rows (half an image row), 4 waves split m-space.
// S^T = mfma(K-frag, Q-frag): lane (g,c) holds (m = 16mt+4g+r, n = 16nt+c).
// P slot layout per wave: [nt][mt][g][c] of uint2 (4 packed bf16 per lane).
// PV A-frag (lane g,c needs P[m=32mc+8g+j][n=c]): two b64 reads at
//   [nt][2mc+(g>>1)][2(g&1)][c] and [nt][2mc+(g>>1)][2(g&1)+1][c].
__global__ __launch_bounds__(256, 4) void attn_kernel(
    const __hip_bfloat16* __restrict__ q_t,  // (4096,256), pre-scaled by 32^-.5*log2e
    const __hip_bfloat16* __restrict__ k_t,  // (4096,256)
    const __hip_bfloat16* __restrict__ vv,   // (256,4096)
    const float* __restrict__ beta_p,
    __hip_bfloat16* __restrict__ att)        // (4096,256)
{
    __shared__ __align__(16) char smem[17920];
    const int h = blockIdx.y;
    const int nb2 = blockIdx.x;
    const int n0 = nb2 * 32;
    const int yq = nb2 >> 1;          // query image row
    const int half = nb2 & 1;
    const int tid = threadIdx.x;
    const int w = tid >> 6, lane = tid & 63, g = lane >> 4, c = lane & 15;

    const float bta = fabsf(beta_p[0]) + 1e-6f;
    const float L2E = 1.4426950408889634f;
    const float c2 = L2E / bta;                       // exp(-d/b) == exp2(-d*c2)

    // bias table: L2E * exp(-|xn-xm|/b); xn-xm = 16*(dlt-3) + 32*half + c - 4g - r
    float d64d[5][4];
#pragma unroll
    for (int dlt = 0; dlt < 5; ++dlt)
#pragma unroll
        for (int r = 0; r < 4; ++r) {
            const int dd = 16 * (dlt - 3) + 32 * half + c - 4 * g - r;
            d64d[dlt][r] = L2E * exp2f(-c2 * fabsf((float)dd));
        }

    bf16x8 aq[2];
#pragma unroll
    for (int nt = 0; nt < 2; ++nt)
        aq[nt] = *reinterpret_cast<const bf16x8*>(
            q_t + (size_t)(n0 + nt * 16 + c) * 256 + h * 32 + g * 8);

    f32x4 o_acc[2][2];
    float l_part[2] = {0.f, 0.f};
#pragma unroll
    for (int nt = 0; nt < 2; ++nt) {
        o_acc[nt][0] = (f32x4){0.f, 0.f, 0.f, 0.f};
        o_acc[nt][1] = (f32x4){0.f, 0.f, 0.f, 0.f};
    }

    uint2* pl = (uint2*)smem + w * 512;              // 4096 B per wave
    const int wbi = g * 16 + c;                      // write slot (uint2 units)
    const int rb = (g >> 1) * 64 + (g & 1) * 32 + c; // read slot base

    const f32x4 zf = (f32x4){0.f, 0.f, 0.f, 0.f};
    for (int it = 0; it < 16; ++it) {
        const int ym = it * 4 + w;
        const size_t m0 = (size_t)ym * 64;
        bf16x8 bk[4];
#pragma unroll
        for (int mt = 0; mt < 4; ++mt)
            bk[mt] = *reinterpret_cast<const bf16x8*>(
                k_t + (m0 + mt * 16 + c) * 256 + h * 32 + g * 8);
        bf16x8 bv[2][2];
#pragma unroll
        for (int dt = 0; dt < 2; ++dt)
#pragma unroll
            for (int mc = 0; mc < 2; ++mc)
                bv[dt][mc] = *reinterpret_cast<const bf16x8*>(
                    vv + (size_t)(h * 32 + dt * 16 + c) * 4096 + m0 + mc * 32 + g * 8);

        const float a2 = exp2f(-c2 * fabsf((float)(yq - ym)));  // exp(-|dy|/b)

#pragma unroll
        for (int nt = 0; nt < 2; ++nt) {
            f32x4 s[4];
#pragma unroll
            for (int mt = 0; mt < 4; ++mt) s[mt] = mfma16(bk[mt], aq[nt], zf);
#pragma unroll
            for (int mt = 0; mt < 4; ++mt) {
                float p[4];
#pragma unroll
                for (int r = 0; r < 4; ++r)
                    p[r] = exp2f(fmaf(a2, d64d[nt - mt + 3][r], s[mt][r]));
                l_part[nt] += (p[0] + p[1]) + (p[2] + p[3]);
                pl[wbi + (nt * 4 + mt) * 64] = uint2{pack_bf16(p[0], p[1]),
                                                     pack_bf16(p[2], p[3])};
            }
        }

#pragma unroll
        for (int nt = 0; nt < 2; ++nt)
#pragma unroll
            for (int mc = 0; mc < 2; ++mc) {
                const int idx = rb + (nt * 4 + 2 * mc) * 64;
                union { uint2 u[2]; bf16x8 v; } t;
                t.u[0] = pl[idx];
                t.u[1] = pl[idx + 16];
                o_acc[nt][0] = mfma16(t.v, bv[0][mc], o_acc[nt][0]);
                o_acc[nt][1] = mfma16(t.v, bv[1][mc], o_acc[nt][1]);
            }
    }

    // reduce l across the 4 g-groups (n = c for both nt)
#pragma unroll
    for (int nt = 0; nt < 2; ++nt) {
        float v = l_part[nt];
        v += __shfl_xor(v, 16);
        v += __shfl_xor(v, 32);
        l_part[nt] = v;
    }

    __syncthreads();
    float* ob = (float*)smem;                  // [w][32][33]
    float* lred = (float*)(smem + 16896);      // [w][32]
#pragma unroll
    for (int nt = 0; nt < 2; ++nt) {
        if (g == 0) lred[w * 32 + nt * 16 + c] = l_part[nt];
#pragma unroll
        for (int r = 0; r < 4; ++r) {
            const int row = 16 * nt + 4 * g + r;
            ob[w * 1056 + row * 33 + c] = o_acc[nt][0][r];
            ob[w * 1056 + row * 33 + 16 + c] = o_acc[nt][1][r];
        }
    }
    __syncthreads();

#pragma unroll
    for (int k = 0; k < 4; ++k) {
        const int flat = k * 256 + tid;
        const int row = flat >> 5, d = flat & 31;
        const float O = ob[row * 33 + d] + ob[1056 + row * 33 + d] +
                        ob[2112 + row * 33 + d] + ob[3168 + row * 33 + d];
        const float L = lred[row] + lred[32 + row] + lred[64 + row] + lred[96 + row];
        att[(size_t)(n0 + row) * 256 + h * 32 + d] = __float2bfloat16(O / L);
    }
}

extern "C" void kernel_launch(void* const* d_in, const int* in_sizes, int n_in,
                              void* d_out, int out_size, void* d_ws, size_t ws_size,
                              hipStream_t stream) {
    (void)in_sizes; (void)n_in; (void)out_size; (void)ws_size;
    const float* x    = (const float*)d_in[0];
    const float* ow   = (const float*)d_in[1];
    const float* w3   = (const float*)d_in[2];
    const float* w5   = (const float*)d_in[3];
    const float* w7   = (const float*)d_in[4];
    const float* wop  = (const float*)d_in[5];
    const float* wq   = (const float*)d_in[6];
    const float* wk   = (const float*)d_in[7];
    const float* wv   = (const float*)d_in[8];
    const float* wo   = (const float*)d_in[9];
    const float* beta = (const float*)d_in[10];

    char* ws = (char*)d_ws;
    const size_t MB = 1 << 20;
    float*          xTf = (float*)(ws);                               // 4 MB
    __hip_bfloat16* xTb = (__hip_bfloat16*)(ws + 4 * MB);             // 2 MB
    __hip_bfloat16* xsT = (__hip_bfloat16*)(ws + 6 * MB);             // 2 MB
    __hip_bfloat16* q_t = (__hip_bfloat16*)(ws + 8 * MB);             // 2 MB
    __hip_bfloat16* k_t = (__hip_bfloat16*)(ws + 10 * MB);            // 2 MB
    __hip_bfloat16* vv  = (__hip_bfloat16*)(ws + 12 * MB);            // 2 MB
    __hip_bfloat16* att = (__hip_bfloat16*)(ws + 14 * MB);            // 2 MB
    __hip_bfloat16* wb  = (__hip_bfloat16*)(ws + 16 * MB);            // 512 KB
    float* wcomb        = (float*)(ws + 16 * MB + 512 * 1024);        // 50 KB
    __hip_bfloat16* wob = wb + 3 * 65536;

    transpose_kernel<<<dim3(128, 8), dim3(32, 8), 0, stream>>>(x, xTf, xTb);
    prep_kernel<<<1073, 256, 0, stream>>>(w3, w5, w7, ow, wq, wk, wv, wo, wcomb, wb);
    sample_kernel<<<4096, 256, 0, stream>>>(xTf, wcomb, wop, xsT);
    gemm_qkv<<<dim3(64, 4, 3), 256, 0, stream>>>(xTb, xsT, wb, q_t, k_t, vv);
    attn_kernel<<<dim3(128, 8), 256, 0, stream>>>(q_t, k_t, vv, beta, att);
    gemm_abt<float><<<dim3(4, 64), 256, 0, stream>>>(wob, att, (float*)d_out, 4096);
}

// Round 5
// 163.668 us; speedup vs baseline: 1.4233x; 1.1880x over previous
//
#include <hip/hip_runtime.h>
#include <hip/hip_bf16.h>

// MSDSA: multi-scale deformable self-attention, B=1, C=256, H=W=64, N=4096, 8 heads x 32 dim.
// Inputs/outputs FLOAT32. Pipeline:
//  1) transpose x (C,N) -> xTf (N,C) f32 + xTb (N,C) bf16
//  2) prep: combined dwconv weights -> wcomb (49,256) f32; cast wq(*scaleL2E)/wk/wv/wo -> bf16
//  3) 8-pixel-block conv (sliding window) + offproj -> tanh grid -> bilinear sample -> xsT bf16
//  4) one dispatch: q_t=(xT)(wq^T); k_t=(xsT)(wk^T); vv=(wv)(xsT^T)  (bf16 MFMA)
//  5) flash attention: 64 q-rows/block (halves K/V cache traffic vs 32), K/V ping-pong
//     prefetch, S^T tiles, all-vector LDS P transpose, no-shift softmax
//  6) d_out = (wo)(att^T) f32

typedef __bf16 bf16x8 __attribute__((ext_vector_type(8)));
typedef float f32x4 __attribute__((ext_vector_type(4)));

__device__ __forceinline__ f32x4 mfma16(bf16x8 a, bf16x8 b, f32x4 c) {
    return __builtin_amdgcn_mfma_f32_16x16x32_bf16(a, b, c, 0, 0, 0);
}

// pack two f32 -> one dword of 2 bf16 (truncate)
__device__ __forceinline__ unsigned pack_bf16(float pa, float pb) {
    return __builtin_amdgcn_perm(__float_as_uint(pb), __float_as_uint(pa), 0x07060302u);
}

// ---------------- 1) transpose (256,4096) f32 -> (4096,256) f32 + bf16 ----------------
__global__ void transpose_kernel(const float* __restrict__ x,
                                 float* __restrict__ xTf,
                                 __hip_bfloat16* __restrict__ xTb) {
    __shared__ float tile[32][33];
    const int p0 = blockIdx.x * 32, c0 = blockIdx.y * 32;
    const int tx = threadIdx.x, ty = threadIdx.y; // (32,8)
#pragma unroll
    for (int i = 0; i < 4; ++i)
        tile[ty + i * 8][tx] = x[(size_t)(c0 + ty + i * 8) * 4096 + p0 + tx];
    __syncthreads();
#pragma unroll
    for (int i = 0; i < 4; ++i) {
        const float v = tile[tx][ty + i * 8];
        const size_t o = (size_t)(p0 + ty + i * 8) * 256 + c0 + tx;
        xTf[o] = v;
        xTb[o] = __float2bfloat16(v);
    }
}

// ---------------- 2) prep: wcomb + weight casts (q scaled by scale*log2e) ----------------
__global__ void prep_kernel(const float* __restrict__ w3, const float* __restrict__ w5,
                            const float* __restrict__ w7, const float* __restrict__ ow,
                            const float* __restrict__ wq, const float* __restrict__ wk,
                            const float* __restrict__ wv, const float* __restrict__ wo,
                            float* __restrict__ wcomb, __hip_bfloat16* __restrict__ wb) {
    const int b = blockIdx.x;
    if (b < 49) {
        const int i = b, c = threadIdx.x;
        const int dy = i / 7, dx = i % 7;
        float val = ow[2] * w7[c * 49 + i];
        if (dy >= 1 && dy <= 5 && dx >= 1 && dx <= 5)
            val += ow[1] * w5[c * 25 + (dy - 1) * 5 + (dx - 1)];
        if (dy >= 2 && dy <= 4 && dx >= 2 && dx <= 4)
            val += ow[0] * w3[c * 9 + (dy - 2) * 3 + (dx - 2)];
        wcomb[i * 256 + c] = val;
    } else {
        const int idx = (b - 49) * 256 + threadIdx.x;   // 0..262143
        const int m = idx >> 16;
        const float* src = (m == 0) ? wq : (m == 1) ? wk : (m == 2) ? wv : wo;
        const float sc = (m == 0) ? 0.25507535f : 1.0f;  // 32^-0.5 * log2(e)
        wb[idx] = __float2bfloat16(src[idx & 65535] * sc);
    }
}

// ---------------- 3) offsets + bilinear sample, 8 pixels/block sliding window ----------------
__global__ __launch_bounds__(256) void sample_kernel(
    const float* __restrict__ xTf, const float* __restrict__ wcomb,
    const float* __restrict__ wop, __hip_bfloat16* __restrict__ xsT) {
    const int b = blockIdx.x;          // 0..511
    const int y = b >> 3;              // image row
    const int x0 = (b & 7) * 8;        // first of 8 pixels
    const int c = threadIdx.x;         // channel

    float wc[49];
#pragma unroll
    for (int i = 0; i < 49; ++i) wc[i] = wcomb[i * 256 + c];

    float acc[8];
#pragma unroll
    for (int px = 0; px < 8; ++px) acc[px] = 0.f;

#pragma unroll
    for (int dy = 0; dy < 7; ++dy) {
        const int yy = y + dy - 3;
        if (yy < 0 || yy > 63) continue;   // SAME zero-padding
        float v[14];
#pragma unroll
        for (int j = 0; j < 14; ++j) {
            const int xx = x0 - 3 + j;
            v[j] = (xx >= 0 && xx <= 63) ? xTf[(size_t)(yy * 64 + xx) * 256 + c] : 0.f;
        }
#pragma unroll
        for (int px = 0; px < 8; ++px)
#pragma unroll
            for (int dx = 0; dx < 7; ++dx)
                acc[px] = fmaf(v[px + dx], wc[dy * 7 + dx], acc[px]);
    }

    const float wy = wop[c], wx = wop[256 + c];
    float s[16];
#pragma unroll
    for (int px = 0; px < 8; ++px) {
        const float r = fmaxf(acc[px], 0.f);
        s[px] = wy * r;
        s[8 + px] = wx * r;
    }
#pragma unroll
    for (int off = 1; off < 64; off <<= 1)
#pragma unroll
        for (int i = 0; i < 16; ++i) s[i] += __shfl_xor(s[i], off, 64);

    __shared__ float red[4][16];
    const int lane = c & 63, wid = c >> 6;
    if (lane == 0)
#pragma unroll
        for (int i = 0; i < 16; ++i) red[wid][i] = s[i];
    __syncthreads();

#pragma unroll
    for (int px = 0; px < 8; ++px) {
        const float offy = red[0][px] + red[1][px] + red[2][px] + red[3][px];
        const float offx = red[0][8 + px] + red[1][8 + px] + red[2][8 + px] + red[3][8 + px];
        const int pxa = x0 + px;
        const float refy = ((y + 0.5f) / 63.0f) * 2.0f - 1.0f;
        const float refx = ((pxa + 0.5f) / 63.0f) * 2.0f - 1.0f;
        const float gy = fminf(fmaxf(refy + tanhf(offy) * 2.0f, -1.0f), 1.0f);
        const float gx = fminf(fmaxf(refx + tanhf(offx) * 2.0f, -1.0f), 1.0f);
        const float iy = (gy + 1.0f) * 31.5f;
        const float ix = (gx + 1.0f) * 31.5f;
        const float y0f = floorf(iy), x0f = floorf(ix);
        const float fy = iy - y0f, fx = ix - x0f;
        int yi0 = min(max((int)y0f, 0), 63), xi0 = min(max((int)x0f, 0), 63);
        int yi1 = min(yi0 + 1, 63), xi1 = min(xi0 + 1, 63);
        const float v00 = xTf[(size_t)(yi0 * 64 + xi0) * 256 + c];
        const float v01 = xTf[(size_t)(yi0 * 64 + xi1) * 256 + c];
        const float v10 = xTf[(size_t)(yi1 * 64 + xi0) * 256 + c];
        const float v11 = xTf[(size_t)(yi1 * 64 + xi1) * 256 + c];
        const float out = v00 * (1.f - fx) * (1.f - fy) + v01 * fx * (1.f - fy) +
                          v10 * (1.f - fx) * fy + v11 * fx * fy;
        xsT[(size_t)(y * 64 + pxa) * 256 + c] = __float2bfloat16(out);
    }
}

// ---------------- 4) GEMM body: out(M,N) = A(M,256)*B(N,256)^T ----------------
template <typename OutT>
__device__ __forceinline__ void gemm_body(const __hip_bfloat16* A, const __hip_bfloat16* B,
                                          OutT* out, int ldc, int m0, int n0) {
    const int w = threadIdx.x >> 6, lane = threadIdx.x & 63;
    const int g = lane >> 4, c = lane & 15;
    f32x4 acc[4];
#pragma unroll
    for (int nt = 0; nt < 4; ++nt) acc[nt] = (f32x4){0.f, 0.f, 0.f, 0.f};
    const __hip_bfloat16* Ar = A + (size_t)(m0 + w * 16 + c) * 256 + g * 8;
#pragma unroll
    for (int kc = 0; kc < 8; ++kc) {
        const bf16x8 a = *reinterpret_cast<const bf16x8*>(Ar + kc * 32);
#pragma unroll
        for (int nt = 0; nt < 4; ++nt) {
            const bf16x8 b = *reinterpret_cast<const bf16x8*>(
                B + (size_t)(n0 + nt * 16 + c) * 256 + kc * 32 + g * 8);
            acc[nt] = mfma16(a, b, acc[nt]);
        }
    }
#pragma unroll
    for (int nt = 0; nt < 4; ++nt)
#pragma unroll
        for (int r = 0; r < 4; ++r) {
            const size_t o = (size_t)(m0 + w * 16 + 4 * g + r) * ldc + n0 + nt * 16 + c;
            if constexpr (__is_same(OutT, float)) out[o] = acc[nt][r];
            else out[o] = __float2bfloat16(acc[nt][r]);
        }
}

// fused Q/K/V projections: z=0 Q, z=1 K, z=2 V
__global__ __launch_bounds__(256) void gemm_qkv(const __hip_bfloat16* __restrict__ xq,
                                                const __hip_bfloat16* __restrict__ xs,
                                                const __hip_bfloat16* __restrict__ wb,
                                                __hip_bfloat16* __restrict__ q_t,
                                                __hip_bfloat16* __restrict__ k_t,
                                                __hip_bfloat16* __restrict__ vv) {
    const int z = blockIdx.z;
    if (z == 0)
        gemm_body<__hip_bfloat16>(xq, wb, q_t, 256, blockIdx.x * 64, blockIdx.y * 64);
    else if (z == 1)
        gemm_body<__hip_bfloat16>(xs, wb + 65536, k_t, 256, blockIdx.x * 64, blockIdx.y * 64);
    else
        gemm_body<__hip_bfloat16>(wb + 2 * 65536, xs, vv, 4096, blockIdx.y * 64,
                                  blockIdx.x * 64);
}

template <typename OutT>
__global__ __launch_bounds__(256) void gemm_abt(const __hip_bfloat16* __restrict__ A,
                                                const __hip_bfloat16* __restrict__ B,
                                                OutT* __restrict__ out, int ldc) {
    gemm_body<OutT>(A, B, out, ldc, blockIdx.x * 64, blockIdx.y * 64);
}

// ---------------- 5) flash attention: 64 q-rows/block, K/V prefetch ----------------
// grid (64, 8): block = one query image row (64 rows), 4 waves split m-space
// (wave w: ym = it*4+w). S^T = mfma(K-frag, Q-frag): lane (g,c) holds
// (m = 16mt+4g+r, n = 16nt+c). P slots per wave: [nt][mt][g][c] uint2.
__global__ __launch_bounds__(256, 2) void attn_kernel(
    const __hip_bfloat16* __restrict__ q_t,  // (4096,256), pre-scaled by 32^-.5*log2e
    const __hip_bfloat16* __restrict__ k_t,  // (4096,256)
    const __hip_bfloat16* __restrict__ vv,   // (256,4096)
    const float* __restrict__ beta_p,
    __hip_bfloat16* __restrict__ att)        // (4096,256)
{
    __shared__ __align__(16) char smem[34816];
    const int h = blockIdx.y;
    const int nb = blockIdx.x;        // query image row
    const int n0 = nb * 64;
    const int tid = threadIdx.x;
    const int w = tid >> 6, lane = tid & 63, g = lane >> 4, c = lane & 15;

    const float bta = fabsf(beta_p[0]) + 1e-6f;
    const float L2E = 1.4426950408889634f;
    const float c2 = L2E / bta;                       // exp(-d/b) == exp2(-d*c2)

    // bias table: L2E * exp(-|xn-xm|/b); xn-xm = 16*(dlt-3) + c - 4g - r
    float d64d[7][4];
#pragma unroll
    for (int dlt = 0; dlt < 7; ++dlt)
#pragma unroll
        for (int r = 0; r < 4; ++r) {
            const int dd = 16 * (dlt - 3) + c - 4 * g - r;
            d64d[dlt][r] = L2E * exp2f(-c2 * fabsf((float)dd));
        }

    bf16x8 aq[4];
#pragma unroll
    for (int nt = 0; nt < 4; ++nt)
        aq[nt] = *reinterpret_cast<const bf16x8*>(
            q_t + (size_t)(n0 + nt * 16 + c) * 256 + h * 32 + g * 8);

    f32x4 o_acc[4][2];
    float l_part[4] = {0.f, 0.f, 0.f, 0.f};
#pragma unroll
    for (int nt = 0; nt < 4; ++nt) {
        o_acc[nt][0] = (f32x4){0.f, 0.f, 0.f, 0.f};
        o_acc[nt][1] = (f32x4){0.f, 0.f, 0.f, 0.f};
    }

    uint2* pl = (uint2*)smem + w * 1024;             // 8 KB per wave
    const int wbi = g * 16 + c;                      // write slot (uint2 units)
    const int rb = (g >> 1) * 64 + (g & 1) * 32 + c; // read slot base
    const f32x4 zf = (f32x4){0.f, 0.f, 0.f, 0.f};

    auto loadK = [&](int it, bf16x8* bk) {
        const size_t m0 = (size_t)(it * 4 + w) * 64;
#pragma unroll
        for (int mt = 0; mt < 4; ++mt)
            bk[mt] = *reinterpret_cast<const bf16x8*>(
                k_t + (m0 + mt * 16 + c) * 256 + h * 32 + g * 8);
    };
    auto loadV = [&](int it, bf16x8 (*bv)[2]) {
        const size_t m0 = (size_t)(it * 4 + w) * 64;
#pragma unroll
        for (int dt = 0; dt < 2; ++dt)
#pragma unroll
            for (int mc = 0; mc < 2; ++mc)
                bv[dt][mc] = *reinterpret_cast<const bf16x8*>(
                    vv + (size_t)(h * 32 + dt * 16 + c) * 4096 + m0 + mc * 32 + g * 8);
    };
    auto body = [&](int it, bf16x8* bk, bf16x8 (*bv)[2]) {
        const int ym = it * 4 + w;
        const float a2 = exp2f(-c2 * fabsf((float)(nb - ym)));  // exp(-|dy|/b)
#pragma unroll
        for (int nt = 0; nt < 4; ++nt) {
            f32x4 s[4];
#pragma unroll
            for (int mt = 0; mt < 4; ++mt) s[mt] = mfma16(bk[mt], aq[nt], zf);
#pragma unroll
            for (int mt = 0; mt < 4; ++mt) {
                float p[4];
#pragma unroll
                for (int r = 0; r < 4; ++r)
                    p[r] = exp2f(fmaf(a2, d64d[nt - mt + 3][r], s[mt][r]));
                l_part[nt] += (p[0] + p[1]) + (p[2] + p[3]);
                pl[wbi + (nt * 4 + mt) * 64] = uint2{pack_bf16(p[0], p[1]),
                                                     pack_bf16(p[2], p[3])};
            }
        }
#pragma unroll
        for (int nt = 0; nt < 4; ++nt)
#pragma unroll
            for (int mc = 0; mc < 2; ++mc) {
                const int idx = rb + (nt * 4 + 2 * mc) * 64;
                union { uint2 u[2]; bf16x8 v; } t;
                t.u[0] = pl[idx];
                t.u[1] = pl[idx + 16];
                o_acc[nt][0] = mfma16(t.v, bv[0][mc], o_acc[nt][0]);
                o_acc[nt][1] = mfma16(t.v, bv[1][mc], o_acc[nt][1]);
            }
    };

    bf16x8 bkA[4], bkB[4], bvA[2][2], bvB[2][2];
    loadK(0, bkA);
    loadV(0, bvA);
#pragma unroll 1
    for (int it2 = 0; it2 < 8; ++it2) {
        loadK(2 * it2 + 1, bkB);
        loadV(2 * it2 + 1, bvB);
        body(2 * it2, bkA, bvA);
        if (it2 < 7) {
            loadK(2 * it2 + 2, bkA);
            loadV(2 * it2 + 2, bvA);
        }
        body(2 * it2 + 1, bkB, bvB);
    }

    // reduce l across the 4 g-groups (n = c for all nt)
#pragma unroll
    for (int nt = 0; nt < 4; ++nt) {
        float v = l_part[nt];
        v += __shfl_xor(v, 16);
        v += __shfl_xor(v, 32);
        l_part[nt] = v;
    }

    __syncthreads();
    float* ob = (float*)smem;                  // [w][64][33]
    float* lred = (float*)(smem + 33792);      // [w][64]
#pragma unroll
    for (int nt = 0; nt < 4; ++nt) {
        if (g == 0) lred[w * 64 + nt * 16 + c] = l_part[nt];
#pragma unroll
        for (int r = 0; r < 4; ++r) {
            const int row = 16 * nt + 4 * g + r;
            ob[w * 2112 + row * 33 + c] = o_acc[nt][0][r];
            ob[w * 2112 + row * 33 + 16 + c] = o_acc[nt][1][r];
        }
    }
    __syncthreads();

#pragma unroll
    for (int k = 0; k < 8; ++k) {
        const int flat = k * 256 + tid;
        const int row = flat >> 5, d = flat & 31;
        const float O = ob[row * 33 + d] + ob[2112 + row * 33 + d] +
                        ob[4224 + row * 33 + d] + ob[6336 + row * 33 + d];
        const float L = lred[row] + lred[64 + row] + lred[128 + row] + lred[192 + row];
        att[(size_t)(n0 + row) * 256 + h * 32 + d] = __float2bfloat16(O / L);
    }
}

extern "C" void kernel_launch(void* const* d_in, const int* in_sizes, int n_in,
                              void* d_out, int out_size, void* d_ws, size_t ws_size,
                              hipStream_t stream) {
    (void)in_sizes; (void)n_in; (void)out_size; (void)ws_size;
    const float* x    = (const float*)d_in[0];
    const float* ow   = (const float*)d_in[1];
    const float* w3   = (const float*)d_in[2];
    const float* w5   = (const float*)d_in[3];
    const float* w7   = (const float*)d_in[4];
    const float* wop  = (const float*)d_in[5];
    const float* wq   = (const float*)d_in[6];
    const float* wk   = (const float*)d_in[7];
    const float* wv   = (const float*)d_in[8];
    const float* wo   = (const float*)d_in[9];
    const float* beta = (const float*)d_in[10];

    char* ws = (char*)d_ws;
    const size_t MB = 1 << 20;
    float*          xTf = (float*)(ws);                               // 4 MB
    __hip_bfloat16* xTb = (__hip_bfloat16*)(ws + 4 * MB);             // 2 MB
    __hip_bfloat16* xsT = (__hip_bfloat16*)(ws + 6 * MB);             // 2 MB
    __hip_bfloat16* q_t = (__hip_bfloat16*)(ws + 8 * MB);             // 2 MB
    __hip_bfloat16* k_t = (__hip_bfloat16*)(ws + 10 * MB);            // 2 MB
    __hip_bfloat16* vv  = (__hip_bfloat16*)(ws + 12 * MB);            // 2 MB
    __hip_bfloat16* att = (__hip_bfloat16*)(ws + 14 * MB);            // 2 MB
    __hip_bfloat16* wb  = (__hip_bfloat16*)(ws + 16 * MB);            // 512 KB
    float* wcomb        = (float*)(ws + 16 * MB + 512 * 1024);        // 50 KB
    __hip_bfloat16* wob = wb + 3 * 65536;

    transpose_kernel<<<dim3(128, 8), dim3(32, 8), 0, stream>>>(x, xTf, xTb);
    prep_kernel<<<1073, 256, 0, stream>>>(w3, w5, w7, ow, wq, wk, wv, wo, wcomb, wb);
    sample_kernel<<<512, 256, 0, stream>>>(xTf, wcomb, wop, xsT);
    gemm_qkv<<<dim3(64, 4, 3), 256, 0, stream>>>(xTb, xsT, wb, q_t, k_t, vv);
    attn_kernel<<<dim3(64, 8), 256, 0, stream>>>(q_t, k_t, vv, beta, att);
    gemm_abt<float><<<dim3(4, 64), 256, 0, stream>>>(wob, att, (float*)d_out, 4096);
}